// Round 1
// baseline (126.851 us; speedup 1.0000x reference)
//
#include <hip/hip_runtime.h>

// Reference analysis: logits = sim - max(sim) (GLOBAL scalar max) is <= 0
// everywhere, so relu(logits) == 0 identically, attn == 0, out == 0.
// The entire (out, attn) tuple is exactly zero for any finite input.
// Kernel reduces to zero-filling d_out (1.09 GB of f32) — pure write stream.

__global__ void zero_out_kernel(float* __restrict__ out, long long n) {
    const long long n4 = n >> 2;               // number of float4s
    float4* __restrict__ out4 = reinterpret_cast<float4*>(out);
    const long long tid    = (long long)blockIdx.x * blockDim.x + threadIdx.x;
    const long long stride = (long long)gridDim.x * blockDim.x;
    const float4 z = make_float4(0.f, 0.f, 0.f, 0.f);
    for (long long j = tid; j < n4; j += stride) {
        out4[j] = z;
    }
    // tail (out_size % 4) — handled by one thread; here out_size is
    // divisible by 4 so this loop is empty, kept for generality.
    if (tid == 0) {
        for (long long j = n4 << 2; j < n; ++j) out[j] = 0.f;
    }
}

extern "C" void kernel_launch(void* const* d_in, const int* in_sizes, int n_in,
                              void* d_out, int out_size, void* d_ws, size_t ws_size,
                              hipStream_t stream) {
    (void)d_in; (void)in_sizes; (void)n_in; (void)d_ws; (void)ws_size;
    float* out = reinterpret_cast<float*>(d_out);
    const long long n = (long long)out_size;   // 272,629,760 f32 ≈ 1.09 GB
    const int block = 256;
    const int grid  = 2048;                    // grid-stride; ~130 float4s/thread
    zero_out_kernel<<<grid, block, 0, stream>>>(out, n);
}